// Round 16
// baseline (84.307 us; speedup 1.0000x reference)
//
#include <hip/hip_runtime.h>
#include <math.h>
#include <stdint.h>

#define NB 4
#define CC 256
#define HWD 4096
#define NPIX (NB * HWD)

typedef __attribute__((ext_vector_type(4))) float f32x4;
typedef __attribute__((ext_vector_type(2))) long i64x2;

#define VMW4()  asm volatile("s_waitcnt vmcnt(4)" ::: "memory")
#define VMW0()  asm volatile("s_waitcnt vmcnt(0)" ::: "memory")
#define LGKM0() asm volatile("s_waitcnt lgkmcnt(0)" ::: "memory")
#define SCHED0() __builtin_amdgcn_sched_barrier(0)
#define SBAR()  __builtin_amdgcn_s_barrier()

__device__ __forceinline__ void gload16(const void* g, void* l) {
    using GP = const __attribute__((address_space(1))) uint32_t*;
    using LP = __attribute__((address_space(3))) uint32_t*;
    __builtin_amdgcn_global_load_lds((GP)g, (LP)l, 16, 0, 0);
}

// sum over each 16-lane DPP row; result valid in lane (rl==15) of each row
__device__ __forceinline__ float dpp_rowsum16(float v) {
    v += __int_as_float(__builtin_amdgcn_update_dpp(0, __float_as_int(v), 0x111, 0xf, 0xf, true));
    v += __int_as_float(__builtin_amdgcn_update_dpp(0, __float_as_int(v), 0x112, 0xf, 0xf, true));
    v += __int_as_float(__builtin_amdgcn_update_dpp(0, __float_as_int(v), 0x114, 0xf, 0xf, true));
    v += __int_as_float(__builtin_amdgcn_update_dpp(0, __float_as_int(v), 0x118, 0xf, 0xf, true));
    return v;
}

// ---------------- kernel 1: per-pixel L2 norm + scale + fp8(e4m3) + transpose ----------------
// Output layout (k-interleaved, same permutation for A and B — dot-product invariant):
// per pixel row, 64-byte K-window w, 16B block g holds channels
// {w*64 + 8g + 0..7} (bytes 0-7) and {w*64 + 32 + 8g + 0..7} (bytes 8-15).
__global__ __launch_bounds__(512) void normcvt(
    const float* __restrict__ rgb, const float* __restrict__ ir,
    unsigned char* __restrict__ Abf, unsigned char* __restrict__ Bbf)
{
    __shared__ float ssbuf[8][64];
    __shared__ float rnl[64];
    const float* src = blockIdx.y ? ir : rgb;
    unsigned char* dst = blockIdx.y ? Bbf : Abf;
    const int t = threadIdx.x;
    const int p = t & 63, sg = t >> 6;
    const int P = blockIdx.x * 64 + p;
    const int n = P >> 12, pl = P & (HWD - 1);
    const float* base = src + ((size_t)n * CC) * HWD + pl;
    const int c0 = sg * 32;              // thread covers channels [c0, c0+32)

    float x[32];
    float ss = 0.f;
#pragma unroll
    for (int i = 0; i < 32; ++i) {
        x[i] = base[(size_t)(c0 + i) * HWD];
        ss = fmaf(x[i], x[i], ss);
    }
    ssbuf[sg][p] = ss;
    __syncthreads();
    if (t < 64) {
        float s2 = 0.f;
#pragma unroll
        for (int g = 0; g < 8; ++g) s2 += ssbuf[g][t];
        rnl[t] = 1.0f / fmaxf(sqrtf(s2), 1e-12f);
    }
    __syncthreads();
    const float rn = rnl[p];

    uint pk[8];
#pragma unroll
    for (int i = 0; i < 8; ++i) {
        int v = __builtin_amdgcn_cvt_pk_fp8_f32(x[4 * i] * rn, x[4 * i + 1] * rn, 0, false);
        v = __builtin_amdgcn_cvt_pk_fp8_f32(x[4 * i + 2] * rn, x[4 * i + 3] * rn, v, true);
        pk[i] = (uint)v;
    }
    // window w = sg>>1; lower-half threads (sg even) fill bytes 0-7 of each block,
    // upper-half threads (sg odd) fill bytes 8-15.
    uint2* o = (uint2*)(dst + (size_t)P * CC + (sg >> 1) * 64 + (sg & 1) * 8);
#pragma unroll
    for (int g = 0; g < 4; ++g)
        o[g * 2] = make_uint2(pk[2 * g], pk[2 * g + 1]);   // stride 16B between blocks
}

// ---------------- kernel 2: 128x128-tile fp8 MFMA GEMM, double-buffer, low arch-VGPR ----
// 4 waves (2x2 of 64x64), BK=64 fp8, 2x8KB buffers/matrix = 32 KB. Arch regs trimmed
// to <=64 (frag/stage addresses = 2 bases + compile-time offsets; chunk swizzle
// (r>>1)&3 is mi/ni/wr/wc-independent) so arch(<=64) + acc(64 AGPR) fits the
// 4-waves/SIMD tier -> 4 blocks/CU. launch_bounds(256,4) enforces it.
__global__ __launch_bounds__(256, 4) void gemm_mfma(
    const unsigned char* __restrict__ Abf, const unsigned char* __restrict__ Bbf,
    const int* __restrict__ rmask, const int* __restrict__ imask,
    float2* __restrict__ prow, float2* __restrict__ pcol)
{
    __shared__ __align__(16) unsigned char As[2][128][64];   // 16 KB
    __shared__ __align__(16) unsigned char Bs[2][128][64];   // 16 KB

    const int n  = blockIdx.z;
    // XCD-aware bijective swizzle within the 32x32 slice (1024 % 8 == 0)
    const int lin = blockIdx.y * 32 + blockIdx.x;
    const int swz = (lin & 7) * 128 + (lin >> 3);
    const int qt = swz & 31, pt = swz >> 5;
    const int q0 = qt * 128, p0 = pt * 128;

    const int t  = threadIdx.x;
    const int lane = t & 63;
    const int wv = t >> 6, wr = wv >> 1, wc = wv & 1;
    const int kg = lane >> 4, rl = lane & 15;

    // ---- stage bases (it=0); it=1 adds +16384 global / +4096 LDS ----
    // slot = it*256+t -> row r = it*64 + (t>>2), pos = t&3; g = pos ^ ((r>>1)&3)
    // (r>>1)&3 = ((t>>2)>>1)&3  [it*64 contributes 32 ≡ 0 mod 4]
    {
    }
    const int srow = t >> 2;
    const int sg_ = (t & 3) ^ ((srow >> 1) & 3);
    const unsigned char* gA0 = Abf + ((size_t)n * HWD + p0 + srow) * CC + sg_ * 16;
    const unsigned char* gB0 = Bbf + ((size_t)n * HWD + q0 + srow) * CC + sg_ * 16;
    char* lA0 = ((char*)As) + (t & 192) * 16;
    char* lB0 = ((char*)Bs) + (t & 192) * 16;

    // one buffer = 8192 bytes -> BUFB in {0, 8192}; C0 = K-step*64 bytes
#define STAGE(BUFB, C0)                                                        \
    {                                                                          \
        gload16(gA0 + (C0), lA0 + (BUFB));                                     \
        gload16(gB0 + (C0), lB0 + (BUFB));                                     \
        gload16(gA0 + 16384 + (C0), lA0 + 4096 + (BUFB));                      \
        gload16(gB0 + 16384 + (C0), lB0 + 4096 + (BUFB));                      \
    }

    // ---- fragment bases: chunk = kg ^ ((rl>>1)&3) uniform across mi/ni ----
    const int chunk = kg ^ ((rl >> 1) & 3);
    const char* apb = ((const char*)As) + (wr * 64 + rl) * 64 + chunk * 16;
    const char* bpb = ((const char*)Bs) + (wc * 64 + rl) * 64 + chunk * 16;

    f32x4 acc[4][4];
#pragma unroll
    for (int mi = 0; mi < 4; ++mi)
#pragma unroll
        for (int ni = 0; ni < 4; ++ni) acc[mi][ni] = (f32x4){0.f, 0.f, 0.f, 0.f};

    STAGE(0, 0);        // K-step 0 -> buf0 (4 loads in flight)
    STAGE(8192, 64);    // K-step 1 -> buf1 (8 in flight)
    SCHED0();

    // KITER: wait this buffer staged -> barrier -> ds_read frags (base + imm offsets)
    // -> lgkm0 -> barrier (all waves done reading) -> restage this buffer -> MFMA.
#define KITER(BUFB, VMWAIT, RESTAGE)                                           \
    {                                                                          \
        VMWAIT;                                                                \
        SCHED0();                                                              \
        SBAR();                                                                \
        SCHED0();                                                              \
        i64x2 aa[4], bb[4];                                                    \
        _Pragma("unroll")                                                      \
        for (int mi = 0; mi < 4; ++mi)                                         \
            aa[mi] = *(const i64x2*)(apb + (BUFB) + mi * 1024);                \
        _Pragma("unroll")                                                      \
        for (int ni = 0; ni < 4; ++ni)                                         \
            bb[ni] = *(const i64x2*)(bpb + (BUFB) + ni * 1024);                \
        LGKM0();                                                               \
        SCHED0();                                                              \
        SBAR();                                                                \
        SCHED0();                                                              \
        RESTAGE;                                                               \
        __builtin_amdgcn_s_setprio(1);                                         \
        _Pragma("unroll")                                                      \
        for (int mi = 0; mi < 4; ++mi)                                         \
            _Pragma("unroll")                                                  \
            for (int ni = 0; ni < 4; ++ni)                                     \
                acc[mi][ni] = __builtin_amdgcn_mfma_f32_16x16x32_fp8_fp8(      \
                    aa[mi][0], bb[ni][0], acc[mi][ni], 0, 0, 0);               \
        _Pragma("unroll")                                                      \
        for (int mi = 0; mi < 4; ++mi)                                         \
            _Pragma("unroll")                                                  \
            for (int ni = 0; ni < 4; ++ni)                                     \
                acc[mi][ni] = __builtin_amdgcn_mfma_f32_16x16x32_fp8_fp8(      \
                    aa[mi][1], bb[ni][1], acc[mi][ni], 0, 0, 0);               \
        __builtin_amdgcn_s_setprio(0);                                         \
        SCHED0();                                                              \
    }

    KITER(0,    VMW4(), STAGE(0, 128));       // step 0 (buf0); restage step2 -> buf0
    KITER(8192, VMW4(), STAGE(8192, 192));    // step 1 (buf1); restage step3 -> buf1
    KITER(0,    VMW4(), );                    // step 2 (buf0)
    KITER(8192, VMW0(), );                    // step 3 (buf1)
#undef KITER
#undef STAGE

    // ---- epilogue: clamp, exp, mask, block-local reduce, partial store (no atomics) ----
    const int* rmp = rmask + (size_t)n * HWD + p0 + wr * 64;
    const int* imp = imask + (size_t)n * HWD + q0 + wc * 64;
    int clab[4];
#pragma unroll
    for (int ni = 0; ni < 4; ++ni) clab[ni] = imp[ni * 16 + rl];

    // LDS scratch aliasing As buf0 (last read at step 2; every wave passed step 2's
    // second barrier — which follows all buf0 lgkm0 drains — before reaching here).
    float* rb = (float*)As;      // [wc][nd][128 rows] = 512 floats
    float* cb = rb + 512;        // [wr][nd][128 cols] = 512 floats

    const float SC = 28.853900817779268f;   // 20 * log2(e)
    float cn[4] = {0.f, 0.f, 0.f, 0.f}, cd[4] = {0.f, 0.f, 0.f, 0.f};

#pragma unroll
    for (int mi = 0; mi < 4; ++mi) {
        int4 r4 = *(const int4*)(rmp + mi * 16 + kg * 4);
        int rlab[4] = {r4.x, r4.y, r4.z, r4.w};
        float rn4[4] = {0.f, 0.f, 0.f, 0.f}, rd4[4] = {0.f, 0.f, 0.f, 0.f};
#pragma unroll
        for (int ni = 0; ni < 4; ++ni) {
#pragma unroll
            for (int j = 0; j < 4; ++j) {
                float s = fminf(fmaxf(acc[mi][ni][j], -1.f), 1.f);
                float e = exp2f(s * SC);
                rd4[j] += e;
                cd[ni] += e;
                float me = (rlab[j] == clab[ni]) ? e : 0.f;
                rn4[j] += me;
                cn[ni] += me;
            }
        }
#pragma unroll
        for (int j = 0; j < 4; ++j) {
            rn4[j] = dpp_rowsum16(rn4[j]);
            rd4[j] = dpp_rowsum16(rd4[j]);
        }
        if (rl == 15) {
            int row = wr * 64 + mi * 16 + kg * 4;
#pragma unroll
            for (int j = 0; j < 4; ++j) {
                rb[(wc * 2 + 0) * 128 + row + j] = rn4[j];
                rb[(wc * 2 + 1) * 128 + row + j] = rd4[j];
            }
        }
    }
#pragma unroll
    for (int ni = 0; ni < 4; ++ni) {
        cn[ni] += __shfl_xor(cn[ni], 16); cn[ni] += __shfl_xor(cn[ni], 32);
        cd[ni] += __shfl_xor(cd[ni], 16); cd[ni] += __shfl_xor(cd[ni], 32);
    }
    if (kg == 0) {
#pragma unroll
        for (int ni = 0; ni < 4; ++ni) {
            int col = wc * 64 + ni * 16 + rl;
            cb[(wr * 2 + 0) * 128 + col] = cn[ni];
            cb[(wr * 2 + 1) * 128 + col] = cd[ni];
        }
    }
    __syncthreads();
    if (t < 128) {
        float2 r2 = make_float2(rb[t] + rb[256 + t], rb[128 + t] + rb[384 + t]);
        prow[(size_t)qt * NPIX + (size_t)n * HWD + p0 + t] = r2;
        float2 c2 = make_float2(cb[t] + cb[256 + t], cb[128 + t] + cb[384 + t]);
        pcol[(size_t)pt * NPIX + (size_t)n * HWD + q0 + t] = c2;
    }
}

// ---------------- kernel 3: reduce partials + loss entries + global reduce ----------------
__global__ __launch_bounds__(256) void loss_reduce(
    const float2* __restrict__ prow, const float2* __restrict__ pcol,
    const int* __restrict__ rmask, const int* __restrict__ imask,
    float* __restrict__ accum)
{
    __shared__ float sbuf[2][4];
    int idx = blockIdx.x * 256 + threadIdx.x;   // 0 .. 2*NPIX-1
    float num = 0.f, den = 0.f; int fg;
    if (idx < NPIX) {
        fg = rmask[idx] > 0;
#pragma unroll 8
        for (int q = 0; q < 32; ++q) {
            float2 v = prow[(size_t)q * NPIX + idx];
            num += v.x; den += v.y;
        }
    } else {
        int k = idx - NPIX;
        fg = imask[k] > 0;
#pragma unroll 8
        for (int p = 0; p < 32; ++p) {
            float2 v = pcol[(size_t)p * NPIX + k];
            num += v.x; den += v.y;
        }
    }
    float v = 0.f, cnt = 0.f;
    if (fg && num > 0.f) {
        float r = num / (den + 1e-6f);
        v = -__logf(r);
        cnt = 1.f;
    }
#pragma unroll
    for (int m = 1; m <= 32; m <<= 1) {
        v += __shfl_xor(v, m);
        cnt += __shfl_xor(cnt, m);
    }
    int lane = threadIdx.x & 63, wave = threadIdx.x >> 6;
    if (lane == 0) { sbuf[0][wave] = v; sbuf[1][wave] = cnt; }
    __syncthreads();
    if (threadIdx.x == 0) {
        atomicAdd(&accum[0], sbuf[0][0] + sbuf[0][1] + sbuf[0][2] + sbuf[0][3]);
        atomicAdd(&accum[1], sbuf[1][0] + sbuf[1][1] + sbuf[1][2] + sbuf[1][3]);
    }
}

__global__ void finalize(const float* __restrict__ accum, float* __restrict__ out) {
    out[0] = accum[0] / fmaxf(accum[1], 1.0f);
}

// ---------------- launch ----------------
extern "C" void kernel_launch(void* const* d_in, const int* in_sizes, int n_in,
                              void* d_out, int out_size, void* d_ws, size_t ws_size,
                              hipStream_t stream) {
    const float* rgb = (const float*)d_in[0];
    const float* ir  = (const float*)d_in[1];
    const int* rm = (const int*)d_in[2];
    const int* im = (const int*)d_in[3];
    float* out = (float*)d_out;

    const size_t NE = (size_t)NPIX * CC;         // 4 MB fp8 per array
    unsigned char* Abf = (unsigned char*)d_ws;
    unsigned char* Bbf = Abf + NE;
    float2* prow = (float2*)(Bbf + NE);          // 32 * NPIX float2 = 4 MB
    float2* pcol = prow + (size_t)32 * NPIX;     // 4 MB
    float* accum = (float*)(pcol + (size_t)32 * NPIX);  // 2 floats

    hipMemsetAsync(accum, 0, 2 * sizeof(float), stream);

    normcvt<<<dim3(NPIX / 64, 2), 512, 0, stream>>>(rgb, ir, Abf, Bbf);
    gemm_mfma<<<dim3(HWD / 128, HWD / 128, NB), 256, 0, stream>>>(
        Abf, Bbf, rm, im, prow, pcol);
    loss_reduce<<<(2 * NPIX) / 256, 256, 0, stream>>>(prow, pcol, rm, im, accum);
    finalize<<<1, 1, 0, stream>>>(accum, out);
}

// Round 17
// 82.848 us; speedup vs baseline: 1.0176x; 1.0176x over previous
//
#include <hip/hip_runtime.h>
#include <math.h>
#include <stdint.h>

#define NB 4
#define CC 256
#define HWD 4096
#define NPIX (NB * HWD)

typedef __attribute__((ext_vector_type(4))) float f32x4;
typedef __attribute__((ext_vector_type(2))) long i64x2;

#define VMW2()  asm volatile("s_waitcnt vmcnt(2)" ::: "memory")
#define VMW0()  asm volatile("s_waitcnt vmcnt(0)" ::: "memory")
#define LGKM0() asm volatile("s_waitcnt lgkmcnt(0)" ::: "memory")
#define SCHED0() __builtin_amdgcn_sched_barrier(0)
#define SBAR()  __builtin_amdgcn_s_barrier()

__device__ __forceinline__ void gload16(const void* g, void* l) {
    using GP = const __attribute__((address_space(1))) uint32_t*;
    using LP = __attribute__((address_space(3))) uint32_t*;
    __builtin_amdgcn_global_load_lds((GP)g, (LP)l, 16, 0, 0);
}

// sum over each 16-lane DPP row; result valid in lane (rl==15) of each row
__device__ __forceinline__ float dpp_rowsum16(float v) {
    v += __int_as_float(__builtin_amdgcn_update_dpp(0, __float_as_int(v), 0x111, 0xf, 0xf, true));
    v += __int_as_float(__builtin_amdgcn_update_dpp(0, __float_as_int(v), 0x112, 0xf, 0xf, true));
    v += __int_as_float(__builtin_amdgcn_update_dpp(0, __float_as_int(v), 0x114, 0xf, 0xf, true));
    v += __int_as_float(__builtin_amdgcn_update_dpp(0, __float_as_int(v), 0x118, 0xf, 0xf, true));
    return v;
}

// ---------------- kernel 1: per-pixel L2 norm + scale + fp8(e4m3) + transpose ----------------
// Output layout (k-interleaved, same permutation for A and B — dot-product invariant):
// per pixel row, 64-byte K-window w, 16B block g holds channels
// {w*64 + 8g + 0..7} (bytes 0-7) and {w*64 + 32 + 8g + 0..7} (bytes 8-15).
__global__ __launch_bounds__(512) void normcvt(
    const float* __restrict__ rgb, const float* __restrict__ ir,
    unsigned char* __restrict__ Abf, unsigned char* __restrict__ Bbf)
{
    __shared__ float ssbuf[8][64];
    __shared__ float rnl[64];
    const float* src = blockIdx.y ? ir : rgb;
    unsigned char* dst = blockIdx.y ? Bbf : Abf;
    const int t = threadIdx.x;
    const int p = t & 63, sg = t >> 6;
    const int P = blockIdx.x * 64 + p;
    const int n = P >> 12, pl = P & (HWD - 1);
    const float* base = src + ((size_t)n * CC) * HWD + pl;
    const int c0 = sg * 32;              // thread covers channels [c0, c0+32)

    float x[32];
    float ss = 0.f;
#pragma unroll
    for (int i = 0; i < 32; ++i) {
        x[i] = base[(size_t)(c0 + i) * HWD];
        ss = fmaf(x[i], x[i], ss);
    }
    ssbuf[sg][p] = ss;
    __syncthreads();
    if (t < 64) {
        float s2 = 0.f;
#pragma unroll
        for (int g = 0; g < 8; ++g) s2 += ssbuf[g][t];
        rnl[t] = 1.0f / fmaxf(sqrtf(s2), 1e-12f);
    }
    __syncthreads();
    const float rn = rnl[p];

    uint pk[8];
#pragma unroll
    for (int i = 0; i < 8; ++i) {
        int v = __builtin_amdgcn_cvt_pk_fp8_f32(x[4 * i] * rn, x[4 * i + 1] * rn, 0, false);
        v = __builtin_amdgcn_cvt_pk_fp8_f32(x[4 * i + 2] * rn, x[4 * i + 3] * rn, v, true);
        pk[i] = (uint)v;
    }
    // window w = sg>>1; lower-half threads (sg even) fill bytes 0-7 of each block,
    // upper-half threads (sg odd) fill bytes 8-15.
    uint2* o = (uint2*)(dst + (size_t)P * CC + (sg >> 1) * 64 + (sg & 1) * 8);
#pragma unroll
    for (int g = 0; g < 4; ++g)
        o[g * 2] = make_uint2(pk[2 * g], pk[2 * g + 1]);   // stride 16B between blocks
}

// ---------------- kernel 2: 128x128-tile fp8 MFMA GEMM, 8 waves of 64x32 ----------------
// 8 waves (2x4 grid; wave tile 64x32 -> acc[4][2] = 32 AGPR), BK=64 fp8,
// 2x8KB buffers/matrix = 32 KB LDS. launch_bounds(512,4): 128 unified/wave =
// 32 acc + 96 arch budget -> 16 waves/CU (4/SIMD), double the r15 residency.
// Counted vmcnt(2) (never 0 mid-loop); zero-conflict b128 frag reads (r14);
// low 8B = MFMA k-instr 0, high 8B = k-instr 1 (k-interleaved layout above).
__global__ __launch_bounds__(512, 4) void gemm_mfma(
    const unsigned char* __restrict__ Abf, const unsigned char* __restrict__ Bbf,
    const int* __restrict__ rmask, const int* __restrict__ imask,
    float2* __restrict__ prow, float2* __restrict__ pcol)
{
    __shared__ __align__(16) unsigned char As[2][128][64];   // 16 KB
    __shared__ __align__(16) unsigned char Bs[2][128][64];   // 16 KB

    const int n  = blockIdx.z;
    // XCD-aware bijective swizzle within the 32x32 slice (1024 % 8 == 0)
    const int lin = blockIdx.y * 32 + blockIdx.x;
    const int swz = (lin & 7) * 128 + (lin >> 3);
    const int qt = swz & 31, pt = swz >> 5;
    const int q0 = qt * 128, p0 = pt * 128;

    const int t  = threadIdx.x;
    const int lane = t & 63;
    const int wv = t >> 6;                   // 0..7
    const int wr = wv >> 2, wc = wv & 3;     // 2 x 4 wave grid; tile 64x32
    const int kg = lane >> 4, rl = lane & 15;

    // ---- stage addresses: 512 slots of 16B per matrix per K-step (1 gload each) ----
    // slot = t -> row r = t>>2, pos = t&3; global 16B-chunk pre-swizzled g = pos ^ ((r>>1)&3)
    const int srow = t >> 2;
    const int sg_ = (t & 3) ^ ((srow >> 1) & 3);
    const unsigned char* gA0 = Abf + ((size_t)n * HWD + p0 + srow) * CC + sg_ * 16;
    const unsigned char* gB0 = Bbf + ((size_t)n * HWD + q0 + srow) * CC + sg_ * 16;
    char* lA0 = ((char*)As) + (t & 448) * 16;     // wave-uniform base wv*1024
    char* lB0 = ((char*)Bs) + (t & 448) * 16;

    // one buffer = 8192 bytes -> BUFB in {0, 8192}; C0 = K-step*64 bytes
#define STAGE(BUFB, C0)                                                        \
    {                                                                          \
        gload16(gA0 + (C0), lA0 + (BUFB));                                     \
        gload16(gB0 + (C0), lB0 + (BUFB));                                     \
    }

    // ---- fragment bases: chunk = kg ^ ((rl>>1)&3) uniform across mi/ni ----
    const int chunk = kg ^ ((rl >> 1) & 3);
    const char* apb = ((const char*)As) + (wr * 64 + rl) * 64 + chunk * 16;
    const char* bpb = ((const char*)Bs) + (wc * 32 + rl) * 64 + chunk * 16;

    f32x4 acc[4][2];
#pragma unroll
    for (int mi = 0; mi < 4; ++mi)
#pragma unroll
        for (int ni = 0; ni < 2; ++ni) acc[mi][ni] = (f32x4){0.f, 0.f, 0.f, 0.f};

    STAGE(0, 0);        // K-step 0 -> buf0 (2 loads in flight)
    STAGE(8192, 64);    // K-step 1 -> buf1 (4 in flight)
    SCHED0();

    // KITER: wait this buffer staged -> barrier -> ds_read frags (base + imm offsets)
    // -> lgkm0 -> barrier (all waves done reading) -> restage this buffer -> MFMA.
#define KITER(BUFB, VMWAIT, RESTAGE)                                           \
    {                                                                          \
        VMWAIT;                                                                \
        SCHED0();                                                              \
        SBAR();                                                                \
        SCHED0();                                                              \
        i64x2 aa[4], bb[2];                                                    \
        _Pragma("unroll")                                                      \
        for (int mi = 0; mi < 4; ++mi)                                         \
            aa[mi] = *(const i64x2*)(apb + (BUFB) + mi * 1024);                \
        _Pragma("unroll")                                                      \
        for (int ni = 0; ni < 2; ++ni)                                         \
            bb[ni] = *(const i64x2*)(bpb + (BUFB) + ni * 1024);                \
        LGKM0();                                                               \
        SCHED0();                                                              \
        SBAR();                                                                \
        SCHED0();                                                              \
        RESTAGE;                                                               \
        __builtin_amdgcn_s_setprio(1);                                         \
        _Pragma("unroll")                                                      \
        for (int mi = 0; mi < 4; ++mi)                                         \
            _Pragma("unroll")                                                  \
            for (int ni = 0; ni < 2; ++ni)                                     \
                acc[mi][ni] = __builtin_amdgcn_mfma_f32_16x16x32_fp8_fp8(      \
                    aa[mi][0], bb[ni][0], acc[mi][ni], 0, 0, 0);               \
        _Pragma("unroll")                                                      \
        for (int mi = 0; mi < 4; ++mi)                                         \
            _Pragma("unroll")                                                  \
            for (int ni = 0; ni < 2; ++ni)                                     \
                acc[mi][ni] = __builtin_amdgcn_mfma_f32_16x16x32_fp8_fp8(      \
                    aa[mi][1], bb[ni][1], acc[mi][ni], 0, 0, 0);               \
        __builtin_amdgcn_s_setprio(0);                                         \
        SCHED0();                                                              \
    }

    KITER(0,    VMW2(), STAGE(0, 128));       // step 0 (buf0); restage step2 -> buf0
    KITER(8192, VMW2(), STAGE(8192, 192));    // step 1 (buf1); restage step3 -> buf1
    KITER(0,    VMW2(), );                    // step 2 (buf0)
    KITER(8192, VMW0(), );                    // step 3 (buf1)
#undef KITER
#undef STAGE

    // ---- epilogue: clamp, exp, mask, block-local reduce, partial store (no atomics) ----
    const int* rmp = rmask + (size_t)n * HWD + p0 + wr * 64;
    const int* imp = imask + (size_t)n * HWD + q0 + wc * 32;
    int clab[2];
#pragma unroll
    for (int ni = 0; ni < 2; ++ni) clab[ni] = imp[ni * 16 + rl];

    // LDS scratch aliasing As buf0 (last read at step 2; every wave passed step 2's
    // second barrier — which follows all buf0 lgkm0 drains — before reaching here).
    float* rb = (float*)As;      // [dup wc:4][nd:2][128 rows] = 1024 floats
    float* cb = rb + 1024;       // [dup wr:2][nd:2][128 cols] = 512 floats

    const float SC = 28.853900817779268f;   // 20 * log2(e)
    float cn[2] = {0.f, 0.f}, cd[2] = {0.f, 0.f};

#pragma unroll
    for (int mi = 0; mi < 4; ++mi) {
        int4 r4 = *(const int4*)(rmp + mi * 16 + kg * 4);
        int rlab[4] = {r4.x, r4.y, r4.z, r4.w};
        float rn4[4] = {0.f, 0.f, 0.f, 0.f}, rd4[4] = {0.f, 0.f, 0.f, 0.f};
#pragma unroll
        for (int ni = 0; ni < 2; ++ni) {
#pragma unroll
            for (int j = 0; j < 4; ++j) {
                float s = fminf(fmaxf(acc[mi][ni][j], -1.f), 1.f);
                float e = exp2f(s * SC);
                rd4[j] += e;
                cd[ni] += e;
                float me = (rlab[j] == clab[ni]) ? e : 0.f;
                rn4[j] += me;
                cn[ni] += me;
            }
        }
#pragma unroll
        for (int j = 0; j < 4; ++j) {
            rn4[j] = dpp_rowsum16(rn4[j]);
            rd4[j] = dpp_rowsum16(rd4[j]);
        }
        if (rl == 15) {
            int row = wr * 64 + mi * 16 + kg * 4;
#pragma unroll
            for (int j = 0; j < 4; ++j) {
                rb[wc * 256 + row + j]       = rn4[j];
                rb[wc * 256 + 128 + row + j] = rd4[j];
            }
        }
    }
#pragma unroll
    for (int ni = 0; ni < 2; ++ni) {
        cn[ni] += __shfl_xor(cn[ni], 16); cn[ni] += __shfl_xor(cn[ni], 32);
        cd[ni] += __shfl_xor(cd[ni], 16); cd[ni] += __shfl_xor(cd[ni], 32);
    }
    if (kg == 0) {
#pragma unroll
        for (int ni = 0; ni < 2; ++ni) {
            int col = wc * 32 + ni * 16 + rl;
            cb[wr * 256 + col]       = cn[ni];
            cb[wr * 256 + 128 + col] = cd[ni];
        }
    }
    __syncthreads();
    if (t < 128) {
        float2 r2 = make_float2(rb[t] + rb[256 + t] + rb[512 + t] + rb[768 + t],
                                rb[128 + t] + rb[384 + t] + rb[640 + t] + rb[896 + t]);
        prow[(size_t)qt * NPIX + (size_t)n * HWD + p0 + t] = r2;
        float2 c2 = make_float2(cb[t] + cb[256 + t], cb[128 + t] + cb[384 + t]);
        pcol[(size_t)pt * NPIX + (size_t)n * HWD + q0 + t] = c2;
    }
}

// ---------------- kernel 3: reduce partials + loss entries + global reduce ----------------
__global__ __launch_bounds__(256) void loss_reduce(
    const float2* __restrict__ prow, const float2* __restrict__ pcol,
    const int* __restrict__ rmask, const int* __restrict__ imask,
    float* __restrict__ accum)
{
    __shared__ float sbuf[2][4];
    int idx = blockIdx.x * 256 + threadIdx.x;   // 0 .. 2*NPIX-1
    float num = 0.f, den = 0.f; int fg;
    if (idx < NPIX) {
        fg = rmask[idx] > 0;
#pragma unroll 8
        for (int q = 0; q < 32; ++q) {
            float2 v = prow[(size_t)q * NPIX + idx];
            num += v.x; den += v.y;
        }
    } else {
        int k = idx - NPIX;
        fg = imask[k] > 0;
#pragma unroll 8
        for (int p = 0; p < 32; ++p) {
            float2 v = pcol[(size_t)p * NPIX + k];
            num += v.x; den += v.y;
        }
    }
    float v = 0.f, cnt = 0.f;
    if (fg && num > 0.f) {
        float r = num / (den + 1e-6f);
        v = -__logf(r);
        cnt = 1.f;
    }
#pragma unroll
    for (int m = 1; m <= 32; m <<= 1) {
        v += __shfl_xor(v, m);
        cnt += __shfl_xor(cnt, m);
    }
    int lane = threadIdx.x & 63, wave = threadIdx.x >> 6;
    if (lane == 0) { sbuf[0][wave] = v; sbuf[1][wave] = cnt; }
    __syncthreads();
    if (threadIdx.x == 0) {
        atomicAdd(&accum[0], sbuf[0][0] + sbuf[0][1] + sbuf[0][2] + sbuf[0][3]);
        atomicAdd(&accum[1], sbuf[1][0] + sbuf[1][1] + sbuf[1][2] + sbuf[1][3]);
    }
}

__global__ void finalize(const float* __restrict__ accum, float* __restrict__ out) {
    out[0] = accum[0] / fmaxf(accum[1], 1.0f);
}

// ---------------- launch ----------------
extern "C" void kernel_launch(void* const* d_in, const int* in_sizes, int n_in,
                              void* d_out, int out_size, void* d_ws, size_t ws_size,
                              hipStream_t stream) {
    const float* rgb = (const float*)d_in[0];
    const float* ir  = (const float*)d_in[1];
    const int* rm = (const int*)d_in[2];
    const int* im = (const int*)d_in[3];
    float* out = (float*)d_out;

    const size_t NE = (size_t)NPIX * CC;         // 4 MB fp8 per array
    unsigned char* Abf = (unsigned char*)d_ws;
    unsigned char* Bbf = Abf + NE;
    float2* prow = (float2*)(Bbf + NE);          // 32 * NPIX float2 = 4 MB
    float2* pcol = prow + (size_t)32 * NPIX;     // 4 MB
    float* accum = (float*)(pcol + (size_t)32 * NPIX);  // 2 floats

    hipMemsetAsync(accum, 0, 2 * sizeof(float), stream);

    normcvt<<<dim3(NPIX / 64, 2), 512, 0, stream>>>(rgb, ir, Abf, Bbf);
    gemm_mfma<<<dim3(HWD / 128, HWD / 128, NB), 512, 0, stream>>>(
        Abf, Bbf, rm, im, prow, pcol);
    loss_reduce<<<(2 * NPIX) / 256, 256, 0, stream>>>(prow, pcol, rm, im, accum);
    finalize<<<1, 1, 0, stream>>>(accum, out);
}

// Round 18
// 75.858 us; speedup vs baseline: 1.1114x; 1.0921x over previous
//
#include <hip/hip_runtime.h>
#include <math.h>
#include <stdint.h>

#define NB 4
#define CC 256
#define HWD 4096
#define NPIX (NB * HWD)

typedef __attribute__((ext_vector_type(4))) float f32x4;
typedef __attribute__((ext_vector_type(2))) long i64x2;

#define VMW4()  asm volatile("s_waitcnt vmcnt(4)" ::: "memory")
#define VMW0()  asm volatile("s_waitcnt vmcnt(0)" ::: "memory")
#define LGKM0() asm volatile("s_waitcnt lgkmcnt(0)" ::: "memory")
#define SCHED0() __builtin_amdgcn_sched_barrier(0)
#define SBAR()  __builtin_amdgcn_s_barrier()

__device__ __forceinline__ void gload16(const void* g, void* l) {
    using GP = const __attribute__((address_space(1))) uint32_t*;
    using LP = __attribute__((address_space(3))) uint32_t*;
    __builtin_amdgcn_global_load_lds((GP)g, (LP)l, 16, 0, 0);
}

// sum over each 16-lane DPP row; result valid in lane (rl==15) of each row
__device__ __forceinline__ float dpp_rowsum16(float v) {
    v += __int_as_float(__builtin_amdgcn_update_dpp(0, __float_as_int(v), 0x111, 0xf, 0xf, true));
    v += __int_as_float(__builtin_amdgcn_update_dpp(0, __float_as_int(v), 0x112, 0xf, 0xf, true));
    v += __int_as_float(__builtin_amdgcn_update_dpp(0, __float_as_int(v), 0x114, 0xf, 0xf, true));
    v += __int_as_float(__builtin_amdgcn_update_dpp(0, __float_as_int(v), 0x118, 0xf, 0xf, true));
    return v;
}

// ---------------- kernel 1: per-pixel L2 norm + scale + fp8(e4m3) + transpose ----------------
// Output layout (k-interleaved, same permutation for A and B — dot-product invariant):
// per pixel row, 64-byte K-window w, 16B block g holds channels
// {w*64 + 8g + 0..7} (bytes 0-7) and {w*64 + 32 + 8g + 0..7} (bytes 8-15).
__global__ __launch_bounds__(512) void normcvt(
    const float* __restrict__ rgb, const float* __restrict__ ir,
    unsigned char* __restrict__ Abf, unsigned char* __restrict__ Bbf)
{
    __shared__ float ssbuf[8][64];
    __shared__ float rnl[64];
    const float* src = blockIdx.y ? ir : rgb;
    unsigned char* dst = blockIdx.y ? Bbf : Abf;
    const int t = threadIdx.x;
    const int p = t & 63, sg = t >> 6;
    const int P = blockIdx.x * 64 + p;
    const int n = P >> 12, pl = P & (HWD - 1);
    const float* base = src + ((size_t)n * CC) * HWD + pl;
    const int c0 = sg * 32;              // thread covers channels [c0, c0+32)

    float x[32];
    float ss = 0.f;
#pragma unroll
    for (int i = 0; i < 32; ++i) {
        x[i] = base[(size_t)(c0 + i) * HWD];
        ss = fmaf(x[i], x[i], ss);
    }
    ssbuf[sg][p] = ss;
    __syncthreads();
    if (t < 64) {
        float s2 = 0.f;
#pragma unroll
        for (int g = 0; g < 8; ++g) s2 += ssbuf[g][t];
        rnl[t] = 1.0f / fmaxf(sqrtf(s2), 1e-12f);
    }
    __syncthreads();
    const float rn = rnl[p];

    uint pk[8];
#pragma unroll
    for (int i = 0; i < 8; ++i) {
        int v = __builtin_amdgcn_cvt_pk_fp8_f32(x[4 * i] * rn, x[4 * i + 1] * rn, 0, false);
        v = __builtin_amdgcn_cvt_pk_fp8_f32(x[4 * i + 2] * rn, x[4 * i + 3] * rn, v, true);
        pk[i] = (uint)v;
    }
    // window w = sg>>1; lower-half threads (sg even) fill bytes 0-7 of each block,
    // upper-half threads (sg odd) fill bytes 8-15.
    uint2* o = (uint2*)(dst + (size_t)P * CC + (sg >> 1) * 64 + (sg & 1) * 8);
#pragma unroll
    for (int g = 0; g < 4; ++g)
        o[g * 2] = make_uint2(pk[2 * g], pk[2 * g + 1]);   // stride 16B between blocks
}

// ---------------- kernel 2: 128x128-tile fp8 MFMA GEMM, double-buffer (32KB LDS) ----------------
// 4 waves (2x2 of 64x64), BK=64 fp8 (64-byte rows), 2x8KB buffers per matrix = 32 KB.
// Counted vmcnt(4) (never 0 mid-loop), restage into the just-freed buffer after
// lgkm0+barrier. Fragments: ONE ds_read_b128 per (mi/ni) at chunk kg^((r>>1)&3) —
// zero-conflict (measured r14); low 8B = MFMA k-instr 0, high 8B = k-instr 1.
// NOTE (r16/r17 lessons): acc[4][4] = 64 AGPR in the unified file; arch need ~84
// -> this config runs at 2 waves/SIMD and that IS the optimum (3 occupancy
// experiments showed more waves/SIMD regresses via +LDS traffic).
__global__ __launch_bounds__(256, 2) void gemm_mfma(
    const unsigned char* __restrict__ Abf, const unsigned char* __restrict__ Bbf,
    const int* __restrict__ rmask, const int* __restrict__ imask,
    float2* __restrict__ prow, float2* __restrict__ pcol)
{
    __shared__ __align__(16) unsigned char As[2][128][64];   // 16 KB
    __shared__ __align__(16) unsigned char Bs[2][128][64];   // 16 KB

    const int n  = blockIdx.z;
    // XCD-aware bijective swizzle within the 32x32 slice (1024 % 8 == 0)
    const int lin = blockIdx.y * 32 + blockIdx.x;
    const int swz = (lin & 7) * 128 + (lin >> 3);
    const int qt = swz & 31, pt = swz >> 5;
    const int q0 = qt * 128, p0 = pt * 128;

    const int t  = threadIdx.x;
    const int lane = t & 63;
    const int wv = t >> 6, wr = wv >> 1, wc = wv & 1;
    const int kg = lane >> 4, rl = lane & 15;

    const unsigned char* Ab = Abf + ((size_t)n * HWD + p0) * CC;
    const unsigned char* Bb = Bbf + ((size_t)n * HWD + q0) * CC;

    // ---- hoisted stage addresses: 2 its x (A,B); 512 16B-slots per matrix per K-step ----
    // slot -> row r = slot>>2, pos = slot&3; global 16B-chunk pre-swizzled g = pos ^ ((r>>1)&3)
    const unsigned char* gA[2]; const unsigned char* gB[2];
    char* lA[2]; char* lB[2];
#pragma unroll
    for (int it = 0; it < 2; ++it) {
        int slot = it * 256 + t;
        int r = slot >> 2, pos = slot & 3;
        int g = pos ^ ((r >> 1) & 3);
        gA[it] = Ab + (size_t)r * CC + g * 16;
        gB[it] = Bb + (size_t)r * CC + g * 16;
        lA[it] = ((char*)As) + it * 4096 + (t & 192) * 16;
        lB[it] = ((char*)Bs) + it * 4096 + (t & 192) * 16;
    }
    // one buffer = 128*64 = 8192 bytes -> BUFB in {0, 8192}; C0 = K-step*64 bytes
#define STAGE(BUFB, C0)                                                        \
    {                                                                          \
        _Pragma("unroll")                                                      \
        for (int it = 0; it < 2; ++it) {                                       \
            gload16(gA[it] + (C0), lA[it] + (BUFB));                           \
            gload16(gB[it] + (C0), lB[it] + (BUFB));                           \
        }                                                                      \
    }

    // ---- hoisted fragment byte addresses (buf0): r*64 + (kg^((r>>1)&3))*16 ----
    const char* ap[4]; const char* bp[4];
#pragma unroll
    for (int mi = 0; mi < 4; ++mi) {
        int r = wr * 64 + mi * 16 + rl;
        ap[mi] = ((const char*)As) + r * 64 + (kg ^ ((r >> 1) & 3)) * 16;
    }
#pragma unroll
    for (int ni = 0; ni < 4; ++ni) {
        int r = wc * 64 + ni * 16 + rl;
        bp[ni] = ((const char*)Bs) + r * 64 + (kg ^ ((r >> 1) & 3)) * 16;
    }

    f32x4 acc[4][4];
#pragma unroll
    for (int mi = 0; mi < 4; ++mi)
#pragma unroll
        for (int ni = 0; ni < 4; ++ni) acc[mi][ni] = (f32x4){0.f, 0.f, 0.f, 0.f};

    STAGE(0, 0);        // K-step 0 -> buf0 (4 loads in flight)
    STAGE(8192, 64);    // K-step 1 -> buf1 (8 in flight)
    SCHED0();

    // KITER: wait this buffer staged -> barrier -> ds_read frags -> lgkm0 ->
    // barrier (all waves done reading) -> restage this buffer -> MFMA.
#define KITER(BUFB, VMWAIT, RESTAGE)                                           \
    {                                                                          \
        VMWAIT;                                                                \
        SCHED0();                                                              \
        SBAR();                                                                \
        SCHED0();                                                              \
        i64x2 aa[4], bb[4];                                                    \
        _Pragma("unroll")                                                      \
        for (int mi = 0; mi < 4; ++mi)                                         \
            aa[mi] = *(const i64x2*)(ap[mi] + (BUFB));                         \
        _Pragma("unroll")                                                      \
        for (int ni = 0; ni < 4; ++ni)                                         \
            bb[ni] = *(const i64x2*)(bp[ni] + (BUFB));                         \
        LGKM0();                                                               \
        SCHED0();                                                              \
        SBAR();                                                                \
        SCHED0();                                                              \
        RESTAGE;                                                               \
        __builtin_amdgcn_s_setprio(1);                                         \
        _Pragma("unroll")                                                      \
        for (int mi = 0; mi < 4; ++mi)                                         \
            _Pragma("unroll")                                                  \
            for (int ni = 0; ni < 4; ++ni)                                     \
                acc[mi][ni] = __builtin_amdgcn_mfma_f32_16x16x32_fp8_fp8(      \
                    aa[mi][0], bb[ni][0], acc[mi][ni], 0, 0, 0);               \
        _Pragma("unroll")                                                      \
        for (int mi = 0; mi < 4; ++mi)                                         \
            _Pragma("unroll")                                                  \
            for (int ni = 0; ni < 4; ++ni)                                     \
                acc[mi][ni] = __builtin_amdgcn_mfma_f32_16x16x32_fp8_fp8(      \
                    aa[mi][1], bb[ni][1], acc[mi][ni], 0, 0, 0);               \
        __builtin_amdgcn_s_setprio(0);                                         \
        SCHED0();                                                              \
    }

    KITER(0,    VMW4(), STAGE(0, 128));       // step 0 (buf0); restage step2 -> buf0
    KITER(8192, VMW4(), STAGE(8192, 192));    // step 1 (buf1); restage step3 -> buf1
    KITER(0,    VMW4(), );                    // step 2 (buf0)
    KITER(8192, VMW0(), );                    // step 3 (buf1)
#undef KITER
#undef STAGE

    // ---- epilogue: clamp, exp, mask, block-local reduce, partial store (no atomics) ----
    const int* rmp = rmask + (size_t)n * HWD + p0 + wr * 64;
    const int* imp = imask + (size_t)n * HWD + q0 + wc * 64;
    int clab[4];
#pragma unroll
    for (int ni = 0; ni < 4; ++ni) clab[ni] = imp[ni * 16 + rl];

    // LDS scratch aliasing As buf0 (last read at step 2; every wave passed step 2's
    // second barrier — which follows all buf0 lgkm0 drains — before reaching here).
    float* rb = (float*)As;      // [wc][nd][128 rows] = 512 floats
    float* cb = rb + 512;        // [wr][nd][128 cols] = 512 floats

    const float SC = 28.853900817779268f;   // 20 * log2(e)
    float cn[4] = {0.f, 0.f, 0.f, 0.f}, cd[4] = {0.f, 0.f, 0.f, 0.f};

#pragma unroll
    for (int mi = 0; mi < 4; ++mi) {
        int4 r4 = *(const int4*)(rmp + mi * 16 + kg * 4);
        int rlab[4] = {r4.x, r4.y, r4.z, r4.w};
        float rn4[4] = {0.f, 0.f, 0.f, 0.f}, rd4[4] = {0.f, 0.f, 0.f, 0.f};
#pragma unroll
        for (int ni = 0; ni < 4; ++ni) {
#pragma unroll
            for (int j = 0; j < 4; ++j) {
                float s = fminf(fmaxf(acc[mi][ni][j], -1.f), 1.f);
                float e = exp2f(s * SC);
                rd4[j] += e;
                cd[ni] += e;
                float me = (rlab[j] == clab[ni]) ? e : 0.f;
                rn4[j] += me;
                cn[ni] += me;
            }
        }
#pragma unroll
        for (int j = 0; j < 4; ++j) {
            rn4[j] = dpp_rowsum16(rn4[j]);
            rd4[j] = dpp_rowsum16(rd4[j]);
        }
        if (rl == 15) {
            int row = wr * 64 + mi * 16 + kg * 4;
#pragma unroll
            for (int j = 0; j < 4; ++j) {
                rb[(wc * 2 + 0) * 128 + row + j] = rn4[j];
                rb[(wc * 2 + 1) * 128 + row + j] = rd4[j];
            }
        }
    }
#pragma unroll
    for (int ni = 0; ni < 4; ++ni) {
        cn[ni] += __shfl_xor(cn[ni], 16); cn[ni] += __shfl_xor(cn[ni], 32);
        cd[ni] += __shfl_xor(cd[ni], 16); cd[ni] += __shfl_xor(cd[ni], 32);
    }
    if (kg == 0) {
#pragma unroll
        for (int ni = 0; ni < 4; ++ni) {
            int col = wc * 64 + ni * 16 + rl;
            cb[(wr * 2 + 0) * 128 + col] = cn[ni];
            cb[(wr * 2 + 1) * 128 + col] = cd[ni];
        }
    }
    __syncthreads();
    if (t < 128) {
        float2 r2 = make_float2(rb[t] + rb[256 + t], rb[128 + t] + rb[384 + t]);
        prow[(size_t)qt * NPIX + (size_t)n * HWD + p0 + t] = r2;
        float2 c2 = make_float2(cb[t] + cb[256 + t], cb[128 + t] + cb[384 + t]);
        pcol[(size_t)pt * NPIX + (size_t)n * HWD + q0 + t] = c2;
    }
}

// ---------------- kernel 3: reduce partials + loss entries + global reduce ----------------
__global__ __launch_bounds__(256) void loss_reduce(
    const float2* __restrict__ prow, const float2* __restrict__ pcol,
    const int* __restrict__ rmask, const int* __restrict__ imask,
    float* __restrict__ accum)
{
    __shared__ float sbuf[2][4];
    int idx = blockIdx.x * 256 + threadIdx.x;   // 0 .. 2*NPIX-1
    float num = 0.f, den = 0.f; int fg;
    if (idx < NPIX) {
        fg = rmask[idx] > 0;
#pragma unroll 8
        for (int q = 0; q < 32; ++q) {
            float2 v = prow[(size_t)q * NPIX + idx];
            num += v.x; den += v.y;
        }
    } else {
        int k = idx - NPIX;
        fg = imask[k] > 0;
#pragma unroll 8
        for (int p = 0; p < 32; ++p) {
            float2 v = pcol[(size_t)p * NPIX + k];
            num += v.x; den += v.y;
        }
    }
    float v = 0.f, cnt = 0.f;
    if (fg && num > 0.f) {
        float r = num / (den + 1e-6f);
        v = -__logf(r);
        cnt = 1.f;
    }
#pragma unroll
    for (int m = 1; m <= 32; m <<= 1) {
        v += __shfl_xor(v, m);
        cnt += __shfl_xor(cnt, m);
    }
    int lane = threadIdx.x & 63, wave = threadIdx.x >> 6;
    if (lane == 0) { sbuf[0][wave] = v; sbuf[1][wave] = cnt; }
    __syncthreads();
    if (threadIdx.x == 0) {
        atomicAdd(&accum[0], sbuf[0][0] + sbuf[0][1] + sbuf[0][2] + sbuf[0][3]);
        atomicAdd(&accum[1], sbuf[1][0] + sbuf[1][1] + sbuf[1][2] + sbuf[1][3]);
    }
}

__global__ void finalize(const float* __restrict__ accum, float* __restrict__ out) {
    out[0] = accum[0] / fmaxf(accum[1], 1.0f);
}

// ---------------- launch ----------------
extern "C" void kernel_launch(void* const* d_in, const int* in_sizes, int n_in,
                              void* d_out, int out_size, void* d_ws, size_t ws_size,
                              hipStream_t stream) {
    const float* rgb = (const float*)d_in[0];
    const float* ir  = (const float*)d_in[1];
    const int* rm = (const int*)d_in[2];
    const int* im = (const int*)d_in[3];
    float* out = (float*)d_out;

    const size_t NE = (size_t)NPIX * CC;         // 4 MB fp8 per array
    unsigned char* Abf = (unsigned char*)d_ws;
    unsigned char* Bbf = Abf + NE;
    float2* prow = (float2*)(Bbf + NE);          // 32 * NPIX float2 = 4 MB
    float2* pcol = prow + (size_t)32 * NPIX;     // 4 MB
    float* accum = (float*)(pcol + (size_t)32 * NPIX);  // 2 floats

    hipMemsetAsync(accum, 0, 2 * sizeof(float), stream);

    normcvt<<<dim3(NPIX / 64, 2), 512, 0, stream>>>(rgb, ir, Abf, Bbf);
    gemm_mfma<<<dim3(HWD / 128, HWD / 128, NB), 256, 0, stream>>>(
        Abf, Bbf, rm, im, prow, pcol);
    loss_reduce<<<(2 * NPIX) / 256, 256, 0, stream>>>(prow, pcol, rm, im, accum);
    finalize<<<1, 1, 0, stream>>>(accum, out);
}